// Round 7
// baseline (449.812 us; speedup 1.0000x reference)
//
#include <hip/hip_runtime.h>

#define NDOF 7
#define BLK 256
#define STAGE (BLK * NDOF)
#define CST_STRIDE 24   // floats per dof block
#define CST_TOT (NDOF * CST_STRIDE)   // 168

// ---------- tiny vec3 ----------
struct V3 { float x, y, z; };
__device__ __forceinline__ V3 operator+(V3 a, V3 b) { return {a.x + b.x, a.y + b.y, a.z + b.z}; }
__device__ __forceinline__ V3 operator-(V3 a, V3 b) { return {a.x - b.x, a.y - b.y, a.z - b.z}; }
__device__ __forceinline__ V3 operator*(float s, V3 a) { return {s * a.x, s * a.y, s * a.z}; }
__device__ __forceinline__ V3 cross(V3 a, V3 b) {
    return {a.y * b.z - a.z * b.y, a.z * b.x - a.x * b.z, a.x * b.y - a.y * b.x};
}
__device__ __forceinline__ float dot(V3 a, V3 b) { return a.x * b.x + a.y * b.y + a.z * b.z; }

// ---------- prep: pack per-dof constants into d_ws ----------
// layout per dof d (stride 24 floats):
//  [0:9)  F columns: Fc0=(F00,F10,F20), Fc1, Fc2
//  [9:12) p = trans_fix[1+d]
//  [12:18) Io6 = I00,I01,I02,I11,I12,I22  (inertia + m*(|c|^2 I - c c^T))
//  [18] m   [19:22) mc = m*com   [22] damping
__global__ void rnea_prep(const float* __restrict__ rot_fix,
                          const float* __restrict__ trans_fix,
                          const float* __restrict__ mass_g,
                          const float* __restrict__ com_g,
                          const float* __restrict__ inertia_g,
                          const float* __restrict__ damping_g,
                          float* __restrict__ cst) {
    const int d = threadIdx.x;
    if (d >= NDOF) return;
    float* o = cst + d * CST_STRIDE;
    const float* F = rot_fix + (1 + d) * 9;
#pragma unroll
    for (int j = 0; j < 3; j++)
#pragma unroll
        for (int i = 0; i < 3; i++) o[j * 3 + i] = F[i * 3 + j];  // column-major
#pragma unroll
    for (int i = 0; i < 3; i++) o[9 + i] = trans_fix[(1 + d) * 3 + i];
    const float m = mass_g[1 + d];
    const float c0 = com_g[(1 + d) * 3 + 0];
    const float c1 = com_g[(1 + d) * 3 + 1];
    const float c2 = com_g[(1 + d) * 3 + 2];
    const float* I = inertia_g + (1 + d) * 9;
    o[12] = I[0] + m * (c1 * c1 + c2 * c2);
    o[13] = I[1] - m * c0 * c1;
    o[14] = I[2] - m * c0 * c2;
    o[15] = I[4] + m * (c0 * c0 + c2 * c2);
    o[16] = I[5] - m * c1 * c2;
    o[17] = I[8] + m * (c0 * c0 + c1 * c1);
    o[18] = m;
    o[19] = m * c0;
    o[20] = m * c1;
    o[21] = m * c2;
    o[22] = damping_g[d];
    o[23] = 0.f;
}

// ---------- per-dof steps, axis known at compile time ----------
// AX: 0 = +z, 1 = +y, 2 = -y   (joint_axes is a literal in the reference)
// C points into LDS: wave-uniform address -> broadcast ds_read, no conflicts.
template <int AX>
__device__ __forceinline__ void make_R(const float* C, float s, float c,
                                       V3& R0, V3& R1, V3& R2) {
    V3 Fc0{C[0], C[1], C[2]}, Fc1{C[3], C[4], C[5]}, Fc2{C[6], C[7], C[8]};
    if (AX == 0) {          // Rq_z cols: (c,s,0), (-s,c,0), (0,0,1)
        R0 = c * Fc0 + s * Fc1;
        R1 = c * Fc1 - s * Fc0;
        R2 = Fc2;
    } else if (AX == 1) {   // Rq_y cols: (c,0,-s), (0,1,0), (s,0,c)
        R0 = c * Fc0 - s * Fc2;
        R1 = Fc1;
        R2 = s * Fc0 + c * Fc2;
    } else {                // Rq_-y cols: (c,0,s), (0,1,0), (-s,0,c)
        R0 = c * Fc0 + s * Fc2;
        R1 = Fc1;
        R2 = c * Fc2 - s * Fc0;
    }
}

template <int AX>
__device__ __forceinline__ void fwd_step(const float* C, float q, float qd, float qdd,
                                         V3& vl, V3& va, V3& al, V3& aa, V3& fl, V3& fa) {
    // __sinf/__cosf only — pointer-form __sincosf escapes an addrspace(5) ptr,
    // defeats SROA, and spilled ~690 B/thread to scratch in round 2.
    const float s = __sinf(q);
    const float c = __cosf(q);
    V3 R0, R1, R2;
    make_R<AX>(C, s, c, R0, R1, R2);
    V3 p{C[9], C[10], C[11]};

    // Rt(vl) + cross(-Rt p, Rt va) == Rt(vl + va x p)
    V3 w1 = vl + cross(va, p);
    V3 w2 = al + cross(aa, p);
    V3 nvl{dot(R0, w1), dot(R1, w1), dot(R2, w1)};
    V3 nva{dot(R0, va), dot(R1, va), dot(R2, va)};
    V3 nal{dot(R0, w2), dot(R1, w2), dot(R2, w2)};
    V3 naa{dot(R0, aa), dot(R1, aa), dot(R2, aa)};

    if (AX == 0) {          // jv=(0,0,qd): cross(v,jv)=(v.y*qd,-v.x*qd,0)
        va = {nva.x, nva.y, nva.z + qd};
        aa = {naa.x + va.y * qd, naa.y - va.x * qd, naa.z + qdd};
        vl = nvl;
        al = {nal.x + vl.y * qd, nal.y - vl.x * qd, nal.z};
    } else if (AX == 1) {   // jv=(0,qd,0): cross(v,jv)=(-v.z*qd,0,v.x*qd)
        va = {nva.x, nva.y + qd, nva.z};
        aa = {naa.x - va.z * qd, naa.y + qdd, naa.z + va.x * qd};
        vl = nvl;
        al = {nal.x - vl.z * qd, nal.y, nal.z + vl.x * qd};
    } else {                // jv=(0,-qd,0): cross(v,jv)=(v.z*qd,0,-v.x*qd)
        va = {nva.x, nva.y - qd, nva.z};
        aa = {naa.x + va.z * qd, naa.y - qdd, naa.z - va.x * qd};
        vl = nvl;
        al = {nal.x + vl.z * qd, nal.y, nal.z - vl.x * qd};
    }

    const float I00 = C[12], I01 = C[13], I02 = C[14], I11 = C[15], I12 = C[16], I22 = C[17];
    const float m = C[18];
    V3 mc{C[19], C[20], C[21]};
    V3 Ial = m * al + cross(aa, mc);
    V3 Iaa = V3{I00 * aa.x + I01 * aa.y + I02 * aa.z,
                I01 * aa.x + I11 * aa.y + I12 * aa.z,
                I02 * aa.x + I12 * aa.y + I22 * aa.z} + cross(mc, al);
    V3 Ivl = m * vl + cross(va, mc);
    V3 Iva = V3{I00 * va.x + I01 * va.y + I02 * va.z,
                I01 * va.x + I11 * va.y + I12 * va.z,
                I02 * va.x + I12 * va.y + I22 * va.z} + cross(mc, vl);
    fl = Ial + cross(va, Ivl);
    fa = Iaa + cross(va, Iva) + cross(vl, Ivl);
}

template <int AX>
__device__ __forceinline__ float bwd_step(const float* C, float q, V3 fl, V3 fa,
                                          V3& cl, V3& ca) {
    // recompute s,c from q (LDS re-read) instead of carrying 14 VGPRs of ss/cc
    const float s = __sinf(q);
    const float c = __cosf(q);
    V3 tl = fl + cl;
    V3 ta = fa + ca;
    float tau;
    if (AX == 0) tau = ta.z;
    else if (AX == 1) tau = ta.y;
    else tau = -ta.y;

    V3 R0, R1, R2;
    make_R<AX>(C, s, c, R0, R1, R2);
    V3 p{C[9], C[10], C[11]};
    V3 nl = tl.x * R0 + tl.y * R1 + tl.z * R2;   // R @ tl (columns)
    V3 na = ta.x * R0 + ta.y * R1 + ta.z * R2 + cross(p, nl);
    cl = nl;
    ca = na;
    return tau;
}

// ---------- main kernel ----------
// waves_per_eu(4): scheduler targets 4 waves/SIMD (<=128 VGPR). The excess
// pressure at 196 VGPR (round 6) was hoisted LDS-constant loads, which the
// scheduler can un-hoist (re-issue broadcast ds_read) instead of spilling.
// Canary for a real spill: WRITE_SIZE >> 14336 KB.
__global__ __launch_bounds__(BLK) __attribute__((amdgpu_waves_per_eu(4)))
void rnea_main(
    const float* __restrict__ q_g, const float* __restrict__ qd_g,
    const float* __restrict__ qdd_g, const float* __restrict__ cst,
    float* __restrict__ out, int n_elem) {
    __shared__ float sQ[STAGE], sQd[STAGE], sQdd[STAGE];
    __shared__ float sC[CST_TOT];
    const int t = threadIdx.x;
    const int base = blockIdx.x * STAGE;

    if (t < CST_TOT) sC[t] = cst[t];   // one coalesced block-wide constant stage

    if (base + STAGE <= n_elem) {
#pragma unroll
        for (int i = t; i < STAGE; i += BLK) {
            const int g = base + i;
            sQ[i] = q_g[g];
            sQd[i] = qd_g[g];
            sQdd[i] = qdd_g[g];
        }
    } else {
#pragma unroll
        for (int i = t; i < STAGE; i += BLK) {
            const int g = base + i;
            const bool ok = g < n_elem;
            sQ[i] = ok ? q_g[g] : 0.f;
            sQd[i] = ok ? qd_g[g] : 0.f;
            sQdd[i] = ok ? qdd_g[g] : 0.f;
        }
    }
    __syncthreads();

    const int o = t * NDOF;
    V3 vl{0.f, 0.f, 0.f}, va{0.f, 0.f, 0.f}, al{0.f, 0.f, 9.81f}, aa{0.f, 0.f, 0.f};
    V3 fl[NDOF], fa[NDOF];

    // axis sequence: z, y, z, -y, z, y, z
    fwd_step<0>(sC + 0 * CST_STRIDE, sQ[o + 0], sQd[o + 0], sQdd[o + 0], vl, va, al, aa, fl[0], fa[0]);
    fwd_step<1>(sC + 1 * CST_STRIDE, sQ[o + 1], sQd[o + 1], sQdd[o + 1], vl, va, al, aa, fl[1], fa[1]);
    fwd_step<0>(sC + 2 * CST_STRIDE, sQ[o + 2], sQd[o + 2], sQdd[o + 2], vl, va, al, aa, fl[2], fa[2]);
    fwd_step<2>(sC + 3 * CST_STRIDE, sQ[o + 3], sQd[o + 3], sQdd[o + 3], vl, va, al, aa, fl[3], fa[3]);
    fwd_step<0>(sC + 4 * CST_STRIDE, sQ[o + 4], sQd[o + 4], sQdd[o + 4], vl, va, al, aa, fl[4], fa[4]);
    fwd_step<1>(sC + 5 * CST_STRIDE, sQ[o + 5], sQd[o + 5], sQdd[o + 5], vl, va, al, aa, fl[5], fa[5]);
    fwd_step<0>(sC + 6 * CST_STRIDE, sQ[o + 6], sQd[o + 6], sQdd[o + 6], vl, va, al, aa, fl[6], fa[6]);

    V3 cl{0.f, 0.f, 0.f}, ca{0.f, 0.f, 0.f};
    float tau[NDOF];
    tau[6] = bwd_step<0>(sC + 6 * CST_STRIDE, sQ[o + 6], fl[6], fa[6], cl, ca);
    tau[5] = bwd_step<1>(sC + 5 * CST_STRIDE, sQ[o + 5], fl[5], fa[5], cl, ca);
    tau[4] = bwd_step<0>(sC + 4 * CST_STRIDE, sQ[o + 4], fl[4], fa[4], cl, ca);
    tau[3] = bwd_step<2>(sC + 3 * CST_STRIDE, sQ[o + 3], fl[3], fa[3], cl, ca);
    tau[2] = bwd_step<0>(sC + 2 * CST_STRIDE, sQ[o + 2], fl[2], fa[2], cl, ca);
    tau[1] = bwd_step<1>(sC + 1 * CST_STRIDE, sQ[o + 1], fl[1], fa[1], cl, ca);
    tau[0] = bwd_step<0>(sC + 0 * CST_STRIDE, sQ[o + 0], fl[0], fa[0], cl, ca);

    __syncthreads();
#pragma unroll
    for (int d = 0; d < NDOF; d++)
        sQ[o + d] = tau[d] + sC[d * CST_STRIDE + 22] * sQd[o + d];
    __syncthreads();
#pragma unroll
    for (int i = t; i < STAGE; i += BLK) {
        const int g = base + i;
        if (g < n_elem) out[g] = sQ[i];
    }
}

extern "C" void kernel_launch(void* const* d_in, const int* in_sizes, int n_in,
                              void* d_out, int out_size, void* d_ws, size_t ws_size,
                              hipStream_t stream) {
    const float* q = (const float*)d_in[0];
    const float* qd = (const float*)d_in[1];
    const float* qdd = (const float*)d_in[2];
    const float* rot_fix = (const float*)d_in[3];
    const float* trans_fix = (const float*)d_in[4];
    // d_in[5] = joint_axes: compile-time constant in the reference (z,y,z,-y,z,y,z)
    const float* mass = (const float*)d_in[6];
    const float* com = (const float*)d_in[7];
    const float* inertia = (const float*)d_in[8];
    const float* damping = (const float*)d_in[9];
    float* out = (float*)d_out;
    float* cst = (float*)d_ws;  // 7*24*4 = 672 B

    const int n_elem = in_sizes[0];  // B * 7
    const int B = n_elem / NDOF;
    const int grid = (B + BLK - 1) / BLK;

    rnea_prep<<<1, 64, 0, stream>>>(rot_fix, trans_fix, mass, com, inertia, damping, cst);
    rnea_main<<<grid, BLK, 0, stream>>>(q, qd, qdd, cst, out, n_elem);
}

// Round 8
// 140.239 us; speedup vs baseline: 3.2075x; 3.2075x over previous
//
#include <hip/hip_runtime.h>

#define NDOF 7
#define BLK 256
#define CST_STRIDE 24               // floats per dof block
#define CST_TOT (NDOF * CST_STRIDE) // 168
#define FREC 43                     // per-thread fl/fa record stride (42 used +1 pad; gcd(43,32)=1)

// ---------- tiny vec3 ----------
struct V3 { float x, y, z; };
__device__ __forceinline__ V3 operator+(V3 a, V3 b) { return {a.x + b.x, a.y + b.y, a.z + b.z}; }
__device__ __forceinline__ V3 operator-(V3 a, V3 b) { return {a.x - b.x, a.y - b.y, a.z - b.z}; }
__device__ __forceinline__ V3 operator*(float s, V3 a) { return {s * a.x, s * a.y, s * a.z}; }
__device__ __forceinline__ V3 cross(V3 a, V3 b) {
    return {a.y * b.z - a.z * b.y, a.z * b.x - a.x * b.z, a.x * b.y - a.y * b.x};
}
__device__ __forceinline__ float dot(V3 a, V3 b) { return a.x * b.x + a.y * b.y + a.z * b.z; }

// ---------- prep: pack per-dof constants into d_ws ----------
// layout per dof d (stride 24 floats):
//  [0:9)  F columns: Fc0=(F00,F10,F20), Fc1, Fc2
//  [9:12) p = trans_fix[1+d]
//  [12:18) Io6 = I00,I01,I02,I11,I12,I22  (inertia + m*(|c|^2 I - c c^T))
//  [18] m   [19:22) mc = m*com   [22] damping
__global__ void rnea_prep(const float* __restrict__ rot_fix,
                          const float* __restrict__ trans_fix,
                          const float* __restrict__ mass_g,
                          const float* __restrict__ com_g,
                          const float* __restrict__ inertia_g,
                          const float* __restrict__ damping_g,
                          float* __restrict__ cst) {
    const int d = threadIdx.x;
    if (d >= NDOF) return;
    float* o = cst + d * CST_STRIDE;
    const float* F = rot_fix + (1 + d) * 9;
#pragma unroll
    for (int j = 0; j < 3; j++)
#pragma unroll
        for (int i = 0; i < 3; i++) o[j * 3 + i] = F[i * 3 + j];  // column-major
#pragma unroll
    for (int i = 0; i < 3; i++) o[9 + i] = trans_fix[(1 + d) * 3 + i];
    const float m = mass_g[1 + d];
    const float c0 = com_g[(1 + d) * 3 + 0];
    const float c1 = com_g[(1 + d) * 3 + 1];
    const float c2 = com_g[(1 + d) * 3 + 2];
    const float* I = inertia_g + (1 + d) * 9;
    o[12] = I[0] + m * (c1 * c1 + c2 * c2);
    o[13] = I[1] - m * c0 * c1;
    o[14] = I[2] - m * c0 * c2;
    o[15] = I[4] + m * (c0 * c0 + c2 * c2);
    o[16] = I[5] - m * c1 * c2;
    o[17] = I[8] + m * (c0 * c0 + c1 * c1);
    o[18] = m;
    o[19] = m * c0;
    o[20] = m * c1;
    o[21] = m * c2;
    o[22] = damping_g[d];
    o[23] = 0.f;
}

// ---------- per-dof steps, axis known at compile time ----------
// AX: 0 = +z, 1 = +y, 2 = -y   (joint_axes is a literal in the reference)
// C points into LDS: wave-uniform address -> broadcast ds_read, no conflicts.
template <int AX>
__device__ __forceinline__ void make_R(const float* C, float s, float c,
                                       V3& R0, V3& R1, V3& R2) {
    V3 Fc0{C[0], C[1], C[2]}, Fc1{C[3], C[4], C[5]}, Fc2{C[6], C[7], C[8]};
    if (AX == 0) {          // Rq_z cols: (c,s,0), (-s,c,0), (0,0,1)
        R0 = c * Fc0 + s * Fc1;
        R1 = c * Fc1 - s * Fc0;
        R2 = Fc2;
    } else if (AX == 1) {   // Rq_y cols: (c,0,-s), (0,1,0), (s,0,c)
        R0 = c * Fc0 - s * Fc2;
        R1 = Fc1;
        R2 = s * Fc0 + c * Fc2;
    } else {                // Rq_-y cols: (c,0,s), (0,1,0), (-s,0,c)
        R0 = c * Fc0 + s * Fc2;
        R1 = Fc1;
        R2 = c * Fc2 - s * Fc0;
    }
}

// fwd: writes fl/fa (6 floats) to the thread's LDS record at link d.
template <int AX>
__device__ __forceinline__ void fwd_step(const float* C, float* frec, float q, float qd,
                                         float qdd, V3& vl, V3& va, V3& al, V3& aa) {
    // __sinf/__cosf only — pointer-form __sincosf escapes an addrspace(5) ptr,
    // defeats SROA, and spilled ~690 B/thread to scratch in round 2.
    const float s = __sinf(q);
    const float c = __cosf(q);
    V3 R0, R1, R2;
    make_R<AX>(C, s, c, R0, R1, R2);
    V3 p{C[9], C[10], C[11]};

    // Rt(vl) + cross(-Rt p, Rt va) == Rt(vl + va x p)
    V3 w1 = vl + cross(va, p);
    V3 w2 = al + cross(aa, p);
    V3 nvl{dot(R0, w1), dot(R1, w1), dot(R2, w1)};
    V3 nva{dot(R0, va), dot(R1, va), dot(R2, va)};
    V3 nal{dot(R0, w2), dot(R1, w2), dot(R2, w2)};
    V3 naa{dot(R0, aa), dot(R1, aa), dot(R2, aa)};

    if (AX == 0) {          // jv=(0,0,qd): cross(v,jv)=(v.y*qd,-v.x*qd,0)
        va = {nva.x, nva.y, nva.z + qd};
        aa = {naa.x + va.y * qd, naa.y - va.x * qd, naa.z + qdd};
        vl = nvl;
        al = {nal.x + vl.y * qd, nal.y - vl.x * qd, nal.z};
    } else if (AX == 1) {   // jv=(0,qd,0): cross(v,jv)=(-v.z*qd,0,v.x*qd)
        va = {nva.x, nva.y + qd, nva.z};
        aa = {naa.x - va.z * qd, naa.y + qdd, naa.z + va.x * qd};
        vl = nvl;
        al = {nal.x - vl.z * qd, nal.y, nal.z + vl.x * qd};
    } else {                // jv=(0,-qd,0): cross(v,jv)=(v.z*qd,0,-v.x*qd)
        va = {nva.x, nva.y - qd, nva.z};
        aa = {naa.x + va.z * qd, naa.y - qdd, naa.z - va.x * qd};
        vl = nvl;
        al = {nal.x + vl.z * qd, nal.y, nal.z - vl.x * qd};
    }

    const float I00 = C[12], I01 = C[13], I02 = C[14], I11 = C[15], I12 = C[16], I22 = C[17];
    const float m = C[18];
    V3 mc{C[19], C[20], C[21]};
    V3 Ial = m * al + cross(aa, mc);
    V3 Iaa = V3{I00 * aa.x + I01 * aa.y + I02 * aa.z,
                I01 * aa.x + I11 * aa.y + I12 * aa.z,
                I02 * aa.x + I12 * aa.y + I22 * aa.z} + cross(mc, al);
    V3 Ivl = m * vl + cross(va, mc);
    V3 Iva = V3{I00 * va.x + I01 * va.y + I02 * va.z,
                I01 * va.x + I11 * va.y + I12 * va.z,
                I02 * va.x + I12 * va.y + I22 * va.z} + cross(mc, vl);
    V3 fl = Ial + cross(va, Ivl);
    V3 fa = Iaa + cross(va, Iva) + cross(vl, Ivl);
    // park in LDS until the backward pass (was 42 long-lived VGPRs in r6)
    frec[0] = fl.x; frec[1] = fl.y; frec[2] = fl.z;
    frec[3] = fa.x; frec[4] = fa.y; frec[5] = fa.z;
}

template <int AX>
__device__ __forceinline__ float bwd_step(const float* C, const float* frec, float q,
                                          V3& cl, V3& ca) {
    // recompute s,c from reg-held q instead of carrying 14 VGPRs of ss/cc
    const float s = __sinf(q);
    const float c = __cosf(q);
    V3 fl{frec[0], frec[1], frec[2]};
    V3 fa{frec[3], frec[4], frec[5]};
    V3 tl = fl + cl;
    V3 ta = fa + ca;
    float tau;
    if (AX == 0) tau = ta.z;
    else if (AX == 1) tau = ta.y;
    else tau = -ta.y;

    V3 R0, R1, R2;
    make_R<AX>(C, s, c, R0, R1, R2);
    V3 p{C[9], C[10], C[11]};
    V3 nl = tl.x * R0 + tl.y * R1 + tl.z * R2;   // R @ tl (columns)
    V3 na = ta.x * R0 + ta.y * R1 + ta.z * R2 + cross(p, nl);
    cl = nl;
    ca = na;
    return tau;
}

// ---------- main kernel ----------
// No allocator-forcing attributes: rounds 2/5/7 showed any occupancy cap on
// this kernel triggers catastrophic scratch spill. Pressure is reduced
// structurally instead (fl/fa in LDS, no input staging arrays).
__global__ __launch_bounds__(BLK) void rnea_main(
    const float* __restrict__ q_g, const float* __restrict__ qd_g,
    const float* __restrict__ qdd_g, const float* __restrict__ cst,
    float* __restrict__ out, int nbatch) {
    __shared__ float sC[CST_TOT];
    __shared__ float sF[BLK * FREC];   // per-thread fl/fa records, 44 KB
    const int t = threadIdx.x;
    const int row = blockIdx.x * BLK + t;

    if (t < CST_TOT) sC[t] = cst[t];
    __syncthreads();

    const bool ok = row < nbatch;
    const size_t go = (size_t)row * NDOF;
    float q[NDOF], qd[NDOF];
    V3 vl{0.f, 0.f, 0.f}, va{0.f, 0.f, 0.f}, al{0.f, 0.f, 9.81f}, aa{0.f, 0.f, 0.f};
    float* frec = sF + t * FREC;

    if (ok) {
        // direct per-thread loads: 7 contiguous floats per array, one clause each
#pragma unroll
        for (int d = 0; d < NDOF; d++) q[d] = q_g[go + d];
#pragma unroll
        for (int d = 0; d < NDOF; d++) qd[d] = qd_g[go + d];
        float qdd[NDOF];
#pragma unroll
        for (int d = 0; d < NDOF; d++) qdd[d] = qdd_g[go + d];

        // axis sequence: z, y, z, -y, z, y, z
        fwd_step<0>(sC + 0 * CST_STRIDE, frec + 0 * 6, q[0], qd[0], qdd[0], vl, va, al, aa);
        fwd_step<1>(sC + 1 * CST_STRIDE, frec + 1 * 6, q[1], qd[1], qdd[1], vl, va, al, aa);
        fwd_step<0>(sC + 2 * CST_STRIDE, frec + 2 * 6, q[2], qd[2], qdd[2], vl, va, al, aa);
        fwd_step<2>(sC + 3 * CST_STRIDE, frec + 3 * 6, q[3], qd[3], qdd[3], vl, va, al, aa);
        fwd_step<0>(sC + 4 * CST_STRIDE, frec + 4 * 6, q[4], qd[4], qdd[4], vl, va, al, aa);
        fwd_step<1>(sC + 5 * CST_STRIDE, frec + 5 * 6, q[5], qd[5], qdd[5], vl, va, al, aa);
        fwd_step<0>(sC + 6 * CST_STRIDE, frec + 6 * 6, q[6], qd[6], qdd[6], vl, va, al, aa);

        V3 cl{0.f, 0.f, 0.f}, ca{0.f, 0.f, 0.f};
        float tau[NDOF];
        tau[6] = bwd_step<0>(sC + 6 * CST_STRIDE, frec + 6 * 6, q[6], cl, ca);
        tau[5] = bwd_step<1>(sC + 5 * CST_STRIDE, frec + 5 * 6, q[5], cl, ca);
        tau[4] = bwd_step<0>(sC + 4 * CST_STRIDE, frec + 4 * 6, q[4], cl, ca);
        tau[3] = bwd_step<2>(sC + 3 * CST_STRIDE, frec + 3 * 6, q[3], cl, ca);
        tau[2] = bwd_step<0>(sC + 2 * CST_STRIDE, frec + 2 * 6, q[2], cl, ca);
        tau[1] = bwd_step<1>(sC + 1 * CST_STRIDE, frec + 1 * 6, q[1], cl, ca);
        tau[0] = bwd_step<0>(sC + 0 * CST_STRIDE, frec + 0 * 6, q[0], cl, ca);

#pragma unroll
        for (int d = 0; d < NDOF; d++)
            out[go + d] = tau[d] + sC[d * CST_STRIDE + 22] * qd[d];
    }
}

extern "C" void kernel_launch(void* const* d_in, const int* in_sizes, int n_in,
                              void* d_out, int out_size, void* d_ws, size_t ws_size,
                              hipStream_t stream) {
    const float* q = (const float*)d_in[0];
    const float* qd = (const float*)d_in[1];
    const float* qdd = (const float*)d_in[2];
    const float* rot_fix = (const float*)d_in[3];
    const float* trans_fix = (const float*)d_in[4];
    // d_in[5] = joint_axes: compile-time constant in the reference (z,y,z,-y,z,y,z)
    const float* mass = (const float*)d_in[6];
    const float* com = (const float*)d_in[7];
    const float* inertia = (const float*)d_in[8];
    const float* damping = (const float*)d_in[9];
    float* out = (float*)d_out;
    float* cst = (float*)d_ws;  // 7*24*4 = 672 B

    const int n_elem = in_sizes[0];  // B * 7
    const int B = n_elem / NDOF;
    const int grid = (B + BLK - 1) / BLK;

    rnea_prep<<<1, 64, 0, stream>>>(rot_fix, trans_fix, mass, com, inertia, damping, cst);
    rnea_main<<<grid, BLK, 0, stream>>>(q, qd, qdd, cst, out, B);
}

// Round 9
// 132.526 us; speedup vs baseline: 3.3942x; 1.0582x over previous
//
#include <hip/hip_runtime.h>

#define NDOF 7
#define BLK 256
#define CST_STRIDE 24               // floats per dof block
#define CST_TOT (NDOF * CST_STRIDE) // 168
#define FREC 43                     // per-thread fl/fa record stride (42 used +1; gcd(43-32=11,32)=1 -> 2-way max)

// ---------- tiny vec3 ----------
struct V3 { float x, y, z; };
__device__ __forceinline__ V3 operator+(V3 a, V3 b) { return {a.x + b.x, a.y + b.y, a.z + b.z}; }
__device__ __forceinline__ V3 operator-(V3 a, V3 b) { return {a.x - b.x, a.y - b.y, a.z - b.z}; }
__device__ __forceinline__ V3 operator*(float s, V3 a) { return {s * a.x, s * a.y, s * a.z}; }
__device__ __forceinline__ V3 cross(V3 a, V3 b) {
    return {a.y * b.z - a.z * b.y, a.z * b.x - a.x * b.z, a.x * b.y - a.y * b.x};
}
__device__ __forceinline__ float dot(V3 a, V3 b) { return a.x * b.x + a.y * b.y + a.z * b.z; }

// ---------- prep: pack per-dof constants into d_ws ----------
// layout per dof d (stride 24 floats):
//  [0:9)  F columns: Fc0=(F00,F10,F20), Fc1, Fc2
//  [9:12) p = trans_fix[1+d]
//  [12:18) Io6 = I00,I01,I02,I11,I12,I22  (inertia + m*(|c|^2 I - c c^T))
//  [18] m   [19:22) mc = m*com   [22] damping
__global__ void rnea_prep(const float* __restrict__ rot_fix,
                          const float* __restrict__ trans_fix,
                          const float* __restrict__ mass_g,
                          const float* __restrict__ com_g,
                          const float* __restrict__ inertia_g,
                          const float* __restrict__ damping_g,
                          float* __restrict__ cst) {
    const int d = threadIdx.x;
    if (d >= NDOF) return;
    float* o = cst + d * CST_STRIDE;
    const float* F = rot_fix + (1 + d) * 9;
#pragma unroll
    for (int j = 0; j < 3; j++)
#pragma unroll
        for (int i = 0; i < 3; i++) o[j * 3 + i] = F[i * 3 + j];  // column-major
#pragma unroll
    for (int i = 0; i < 3; i++) o[9 + i] = trans_fix[(1 + d) * 3 + i];
    const float m = mass_g[1 + d];
    const float c0 = com_g[(1 + d) * 3 + 0];
    const float c1 = com_g[(1 + d) * 3 + 1];
    const float c2 = com_g[(1 + d) * 3 + 2];
    const float* I = inertia_g + (1 + d) * 9;
    o[12] = I[0] + m * (c1 * c1 + c2 * c2);
    o[13] = I[1] - m * c0 * c1;
    o[14] = I[2] - m * c0 * c2;
    o[15] = I[4] + m * (c0 * c0 + c2 * c2);
    o[16] = I[5] - m * c1 * c2;
    o[17] = I[8] + m * (c0 * c0 + c1 * c1);
    o[18] = m;
    o[19] = m * c0;
    o[20] = m * c1;
    o[21] = m * c2;
    o[22] = damping_g[d];
    o[23] = 0.f;
}

// ---------- per-dof steps, axis known at compile time ----------
// AX: 0 = +z, 1 = +y, 2 = -y   (joint_axes is a literal in the reference)
// C points into LDS: wave-uniform address -> broadcast ds_read, no conflicts.
template <int AX>
__device__ __forceinline__ void make_R(const float* C, float s, float c,
                                       V3& R0, V3& R1, V3& R2) {
    V3 Fc0{C[0], C[1], C[2]}, Fc1{C[3], C[4], C[5]}, Fc2{C[6], C[7], C[8]};
    if (AX == 0) {          // Rq_z cols: (c,s,0), (-s,c,0), (0,0,1)
        R0 = c * Fc0 + s * Fc1;
        R1 = c * Fc1 - s * Fc0;
        R2 = Fc2;
    } else if (AX == 1) {   // Rq_y cols: (c,0,-s), (0,1,0), (s,0,c)
        R0 = c * Fc0 - s * Fc2;
        R1 = Fc1;
        R2 = s * Fc0 + c * Fc2;
    } else {                // Rq_-y cols: (c,0,s), (0,1,0), (-s,0,c)
        R0 = c * Fc0 + s * Fc2;
        R1 = Fc1;
        R2 = c * Fc2 - s * Fc0;
    }
}

// fwd: parks fl/fa (6 floats) in the thread's LDS record at link d.
// volatile: round 8 showed the compiler forwards non-volatile same-thread
// LDS write->read and promotes the whole array back into registers
// (LDS_Block_Size collapsed to 1 KB, VGPR stayed 200).
template <int AX>
__device__ __forceinline__ void fwd_step(const float* C, volatile float* frec, float q,
                                         float qd, float qdd, V3& vl, V3& va, V3& al,
                                         V3& aa) {
    // __sinf/__cosf only — pointer-form __sincosf escapes an addrspace(5) ptr,
    // defeats SROA, and spilled ~690 B/thread to scratch in round 2.
    const float s = __sinf(q);
    const float c = __cosf(q);
    V3 R0, R1, R2;
    make_R<AX>(C, s, c, R0, R1, R2);
    V3 p{C[9], C[10], C[11]};

    // Rt(vl) + cross(-Rt p, Rt va) == Rt(vl + va x p)
    V3 w1 = vl + cross(va, p);
    V3 w2 = al + cross(aa, p);
    V3 nvl{dot(R0, w1), dot(R1, w1), dot(R2, w1)};
    V3 nva{dot(R0, va), dot(R1, va), dot(R2, va)};
    V3 nal{dot(R0, w2), dot(R1, w2), dot(R2, w2)};
    V3 naa{dot(R0, aa), dot(R1, aa), dot(R2, aa)};

    if (AX == 0) {          // jv=(0,0,qd): cross(v,jv)=(v.y*qd,-v.x*qd,0)
        va = {nva.x, nva.y, nva.z + qd};
        aa = {naa.x + va.y * qd, naa.y - va.x * qd, naa.z + qdd};
        vl = nvl;
        al = {nal.x + vl.y * qd, nal.y - vl.x * qd, nal.z};
    } else if (AX == 1) {   // jv=(0,qd,0): cross(v,jv)=(-v.z*qd,0,v.x*qd)
        va = {nva.x, nva.y + qd, nva.z};
        aa = {naa.x - va.z * qd, naa.y + qdd, naa.z + va.x * qd};
        vl = nvl;
        al = {nal.x - vl.z * qd, nal.y, nal.z + vl.x * qd};
    } else {                // jv=(0,-qd,0): cross(v,jv)=(v.z*qd,0,-v.x*qd)
        va = {nva.x, nva.y - qd, nva.z};
        aa = {naa.x + va.z * qd, naa.y - qdd, naa.z - va.x * qd};
        vl = nvl;
        al = {nal.x + vl.z * qd, nal.y, nal.z - vl.x * qd};
    }

    const float I00 = C[12], I01 = C[13], I02 = C[14], I11 = C[15], I12 = C[16], I22 = C[17];
    const float m = C[18];
    V3 mc{C[19], C[20], C[21]};
    V3 Ial = m * al + cross(aa, mc);
    V3 Iaa = V3{I00 * aa.x + I01 * aa.y + I02 * aa.z,
                I01 * aa.x + I11 * aa.y + I12 * aa.z,
                I02 * aa.x + I12 * aa.y + I22 * aa.z} + cross(mc, al);
    V3 Ivl = m * vl + cross(va, mc);
    V3 Iva = V3{I00 * va.x + I01 * va.y + I02 * va.z,
                I01 * va.x + I11 * va.y + I12 * va.z,
                I02 * va.x + I12 * va.y + I22 * va.z} + cross(mc, vl);
    V3 fl = Ial + cross(va, Ivl);
    V3 fa = Iaa + cross(va, Iva) + cross(vl, Ivl);
    frec[0] = fl.x; frec[1] = fl.y; frec[2] = fl.z;
    frec[3] = fa.x; frec[4] = fa.y; frec[5] = fa.z;
}

template <int AX>
__device__ __forceinline__ float bwd_step(const float* C, const volatile float* frec,
                                          float q, V3& cl, V3& ca) {
    // recompute s,c from reg-held q instead of carrying 14 VGPRs of ss/cc
    const float s = __sinf(q);
    const float c = __cosf(q);
    V3 fl{frec[0], frec[1], frec[2]};
    V3 fa{frec[3], frec[4], frec[5]};
    V3 tl = fl + cl;
    V3 ta = fa + ca;
    float tau;
    if (AX == 0) tau = ta.z;
    else if (AX == 1) tau = ta.y;
    else tau = -ta.y;

    V3 R0, R1, R2;
    make_R<AX>(C, s, c, R0, R1, R2);
    V3 p{C[9], C[10], C[11]};
    V3 nl = tl.x * R0 + tl.y * R1 + tl.z * R2;   // R @ tl (columns)
    V3 na = ta.x * R0 + ta.y * R1 + ta.z * R2 + cross(p, nl);
    cl = nl;
    ca = na;
    return tau;
}

// ---------- main kernel ----------
// No allocator-forcing attributes: rounds 2/5/7 showed any occupancy cap on
// this kernel triggers catastrophic scratch spill. Pressure is reduced
// structurally (fl/fa genuinely in LDS via volatile; no input staging arrays).
__global__ __launch_bounds__(BLK) void rnea_main(
    const float* __restrict__ q_g, const float* __restrict__ qd_g,
    const float* __restrict__ qdd_g, const float* __restrict__ cst,
    float* __restrict__ out, int nbatch) {
    __shared__ float sC[CST_TOT];
    __shared__ float sF[BLK * FREC];   // per-thread fl/fa records, 44 KB
    const int t = threadIdx.x;
    const int row = blockIdx.x * BLK + t;

    if (t < CST_TOT) sC[t] = cst[t];
    __syncthreads();

    const bool ok = row < nbatch;
    const size_t go = (size_t)row * NDOF;
    float q[NDOF], qd[NDOF];
    V3 vl{0.f, 0.f, 0.f}, va{0.f, 0.f, 0.f}, al{0.f, 0.f, 9.81f}, aa{0.f, 0.f, 0.f};
    volatile float* frec = sF + t * FREC;

    if (ok) {
        // direct per-thread loads: 7 contiguous floats per array, one clause each
#pragma unroll
        for (int d = 0; d < NDOF; d++) q[d] = q_g[go + d];
#pragma unroll
        for (int d = 0; d < NDOF; d++) qd[d] = qd_g[go + d];
        float qdd[NDOF];
#pragma unroll
        for (int d = 0; d < NDOF; d++) qdd[d] = qdd_g[go + d];

        // axis sequence: z, y, z, -y, z, y, z
        fwd_step<0>(sC + 0 * CST_STRIDE, frec + 0 * 6, q[0], qd[0], qdd[0], vl, va, al, aa);
        fwd_step<1>(sC + 1 * CST_STRIDE, frec + 1 * 6, q[1], qd[1], qdd[1], vl, va, al, aa);
        fwd_step<0>(sC + 2 * CST_STRIDE, frec + 2 * 6, q[2], qd[2], qdd[2], vl, va, al, aa);
        fwd_step<2>(sC + 3 * CST_STRIDE, frec + 3 * 6, q[3], qd[3], qdd[3], vl, va, al, aa);
        fwd_step<0>(sC + 4 * CST_STRIDE, frec + 4 * 6, q[4], qd[4], qdd[4], vl, va, al, aa);
        fwd_step<1>(sC + 5 * CST_STRIDE, frec + 5 * 6, q[5], qd[5], qdd[5], vl, va, al, aa);
        fwd_step<0>(sC + 6 * CST_STRIDE, frec + 6 * 6, q[6], qd[6], qdd[6], vl, va, al, aa);

        V3 cl{0.f, 0.f, 0.f}, ca{0.f, 0.f, 0.f};
        float tau[NDOF];
        tau[6] = bwd_step<0>(sC + 6 * CST_STRIDE, frec + 6 * 6, q[6], cl, ca);
        tau[5] = bwd_step<1>(sC + 5 * CST_STRIDE, frec + 5 * 6, q[5], cl, ca);
        tau[4] = bwd_step<0>(sC + 4 * CST_STRIDE, frec + 4 * 6, q[4], cl, ca);
        tau[3] = bwd_step<2>(sC + 3 * CST_STRIDE, frec + 3 * 6, q[3], cl, ca);
        tau[2] = bwd_step<0>(sC + 2 * CST_STRIDE, frec + 2 * 6, q[2], cl, ca);
        tau[1] = bwd_step<1>(sC + 1 * CST_STRIDE, frec + 1 * 6, q[1], cl, ca);
        tau[0] = bwd_step<0>(sC + 0 * CST_STRIDE, frec + 0 * 6, q[0], cl, ca);

#pragma unroll
        for (int d = 0; d < NDOF; d++)
            out[go + d] = tau[d] + sC[d * CST_STRIDE + 22] * qd[d];
    }
}

extern "C" void kernel_launch(void* const* d_in, const int* in_sizes, int n_in,
                              void* d_out, int out_size, void* d_ws, size_t ws_size,
                              hipStream_t stream) {
    const float* q = (const float*)d_in[0];
    const float* qd = (const float*)d_in[1];
    const float* qdd = (const float*)d_in[2];
    const float* rot_fix = (const float*)d_in[3];
    const float* trans_fix = (const float*)d_in[4];
    // d_in[5] = joint_axes: compile-time constant in the reference (z,y,z,-y,z,y,z)
    const float* mass = (const float*)d_in[6];
    const float* com = (const float*)d_in[7];
    const float* inertia = (const float*)d_in[8];
    const float* damping = (const float*)d_in[9];
    float* out = (float*)d_out;
    float* cst = (float*)d_ws;  // 7*24*4 = 672 B

    const int n_elem = in_sizes[0];  // B * 7
    const int B = n_elem / NDOF;
    const int grid = (B + BLK - 1) / BLK;

    rnea_prep<<<1, 64, 0, stream>>>(rot_fix, trans_fix, mass, com, inertia, damping, cst);
    rnea_main<<<grid, BLK, 0, stream>>>(q, qd, qdd, cst, out, B);
}

// Round 10
// 123.216 us; speedup vs baseline: 3.6506x; 1.0756x over previous
//
#include <hip/hip_runtime.h>

#define NDOF 7
#define BLK 256
#define CST_STRIDE 24               // floats per dof block
#define CST_TOT (NDOF * CST_STRIDE) // 168
#define FREC 43                     // per-thread fl/fa record stride (42 used +1; 43 mod 32 = 11, coprime -> conflict-free)

// ---------- tiny vec3 ----------
struct V3 { float x, y, z; };
__device__ __forceinline__ V3 operator+(V3 a, V3 b) { return {a.x + b.x, a.y + b.y, a.z + b.z}; }
__device__ __forceinline__ V3 operator-(V3 a, V3 b) { return {a.x - b.x, a.y - b.y, a.z - b.z}; }
__device__ __forceinline__ V3 operator*(float s, V3 a) { return {s * a.x, s * a.y, s * a.z}; }
__device__ __forceinline__ V3 cross(V3 a, V3 b) {
    return {a.y * b.z - a.z * b.y, a.z * b.x - a.x * b.z, a.x * b.y - a.y * b.x};
}
__device__ __forceinline__ float dot(V3 a, V3 b) { return a.x * b.x + a.y * b.y + a.z * b.z; }

// ---------- prep: pack per-dof constants into d_ws ----------
// layout per dof d (stride 24 floats):
//  [0:9)  F columns: Fc0=(F00,F10,F20), Fc1, Fc2
//  [9:12) p = trans_fix[1+d]
//  [12:18) Io6 = I00,I01,I02,I11,I12,I22  (inertia + m*(|c|^2 I - c c^T))
//  [18] m   [19:22) mc = m*com   [22] damping
__global__ void rnea_prep(const float* __restrict__ rot_fix,
                          const float* __restrict__ trans_fix,
                          const float* __restrict__ mass_g,
                          const float* __restrict__ com_g,
                          const float* __restrict__ inertia_g,
                          const float* __restrict__ damping_g,
                          float* __restrict__ cst) {
    const int d = threadIdx.x;
    if (d >= NDOF) return;
    float* o = cst + d * CST_STRIDE;
    const float* F = rot_fix + (1 + d) * 9;
#pragma unroll
    for (int j = 0; j < 3; j++)
#pragma unroll
        for (int i = 0; i < 3; i++) o[j * 3 + i] = F[i * 3 + j];  // column-major
#pragma unroll
    for (int i = 0; i < 3; i++) o[9 + i] = trans_fix[(1 + d) * 3 + i];
    const float m = mass_g[1 + d];
    const float c0 = com_g[(1 + d) * 3 + 0];
    const float c1 = com_g[(1 + d) * 3 + 1];
    const float c2 = com_g[(1 + d) * 3 + 2];
    const float* I = inertia_g + (1 + d) * 9;
    o[12] = I[0] + m * (c1 * c1 + c2 * c2);
    o[13] = I[1] - m * c0 * c1;
    o[14] = I[2] - m * c0 * c2;
    o[15] = I[4] + m * (c0 * c0 + c2 * c2);
    o[16] = I[5] - m * c1 * c2;
    o[17] = I[8] + m * (c0 * c0 + c1 * c1);
    o[18] = m;
    o[19] = m * c0;
    o[20] = m * c1;
    o[21] = m * c2;
    o[22] = damping_g[d];
    o[23] = 0.f;
}

// ---------- per-dof steps, axis known at compile time ----------
// AX: 0 = +z, 1 = +y, 2 = -y   (joint_axes is a literal in the reference)
// C points into LDS: wave-uniform address -> broadcast ds_read, no conflicts.
template <int AX>
__device__ __forceinline__ void make_R(const float* C, float s, float c,
                                       V3& R0, V3& R1, V3& R2) {
    V3 Fc0{C[0], C[1], C[2]}, Fc1{C[3], C[4], C[5]}, Fc2{C[6], C[7], C[8]};
    if (AX == 0) {          // Rq_z cols: (c,s,0), (-s,c,0), (0,0,1)
        R0 = c * Fc0 + s * Fc1;
        R1 = c * Fc1 - s * Fc0;
        R2 = Fc2;
    } else if (AX == 1) {   // Rq_y cols: (c,0,-s), (0,1,0), (s,0,c)
        R0 = c * Fc0 - s * Fc2;
        R1 = Fc1;
        R2 = s * Fc0 + c * Fc2;
    } else {                // Rq_-y cols: (c,0,s), (0,1,0), (-s,0,c)
        R0 = c * Fc0 + s * Fc2;
        R1 = Fc1;
        R2 = c * Fc2 - s * Fc0;
    }
}

// fwd: parks fl/fa (6 floats) in the thread's LDS record at link d.
// NON-volatile stores: a __syncthreads() between the fwd and bwd passes acts
// as an LDS clobber, so the compiler cannot forward/promote these across it
// (r8: no barrier -> whole array promoted, VGPR 200; r9: volatile -> parked
// but every access serialized with lgkmcnt waits, stalls grew).
template <int AX>
__device__ __forceinline__ void fwd_step(const float* C, float* frec, float q,
                                         float qd, float qdd, V3& vl, V3& va, V3& al,
                                         V3& aa) {
    // __sinf/__cosf only — pointer-form __sincosf escapes an addrspace(5) ptr,
    // defeats SROA, and spilled ~690 B/thread to scratch in round 2.
    const float s = __sinf(q);
    const float c = __cosf(q);
    V3 R0, R1, R2;
    make_R<AX>(C, s, c, R0, R1, R2);
    V3 p{C[9], C[10], C[11]};

    // Rt(vl) + cross(-Rt p, Rt va) == Rt(vl + va x p)
    V3 w1 = vl + cross(va, p);
    V3 w2 = al + cross(aa, p);
    V3 nvl{dot(R0, w1), dot(R1, w1), dot(R2, w1)};
    V3 nva{dot(R0, va), dot(R1, va), dot(R2, va)};
    V3 nal{dot(R0, w2), dot(R1, w2), dot(R2, w2)};
    V3 naa{dot(R0, aa), dot(R1, aa), dot(R2, aa)};

    if (AX == 0) {          // jv=(0,0,qd): cross(v,jv)=(v.y*qd,-v.x*qd,0)
        va = {nva.x, nva.y, nva.z + qd};
        aa = {naa.x + va.y * qd, naa.y - va.x * qd, naa.z + qdd};
        vl = nvl;
        al = {nal.x + vl.y * qd, nal.y - vl.x * qd, nal.z};
    } else if (AX == 1) {   // jv=(0,qd,0): cross(v,jv)=(-v.z*qd,0,v.x*qd)
        va = {nva.x, nva.y + qd, nva.z};
        aa = {naa.x - va.z * qd, naa.y + qdd, naa.z + va.x * qd};
        vl = nvl;
        al = {nal.x - vl.z * qd, nal.y, nal.z + vl.x * qd};
    } else {                // jv=(0,-qd,0): cross(v,jv)=(v.z*qd,0,-v.x*qd)
        va = {nva.x, nva.y - qd, nva.z};
        aa = {naa.x + va.z * qd, naa.y - qdd, naa.z - va.x * qd};
        vl = nvl;
        al = {nal.x + vl.z * qd, nal.y, nal.z - vl.x * qd};
    }

    const float I00 = C[12], I01 = C[13], I02 = C[14], I11 = C[15], I12 = C[16], I22 = C[17];
    const float m = C[18];
    V3 mc{C[19], C[20], C[21]};
    V3 Ial = m * al + cross(aa, mc);
    V3 Iaa = V3{I00 * aa.x + I01 * aa.y + I02 * aa.z,
                I01 * aa.x + I11 * aa.y + I12 * aa.z,
                I02 * aa.x + I12 * aa.y + I22 * aa.z} + cross(mc, al);
    V3 Ivl = m * vl + cross(va, mc);
    V3 Iva = V3{I00 * va.x + I01 * va.y + I02 * va.z,
                I01 * va.x + I11 * va.y + I12 * va.z,
                I02 * va.x + I12 * va.y + I22 * va.z} + cross(mc, vl);
    V3 fl = Ial + cross(va, Ivl);
    V3 fa = Iaa + cross(va, Iva) + cross(vl, Ivl);
    frec[0] = fl.x; frec[1] = fl.y; frec[2] = fl.z;
    frec[3] = fa.x; frec[4] = fa.y; frec[5] = fa.z;
}

template <int AX>
__device__ __forceinline__ float bwd_step(const float* C, const float* frec,
                                          float q, V3& cl, V3& ca) {
    // recompute s,c from reg-held q instead of carrying 14 VGPRs of ss/cc
    const float s = __sinf(q);
    const float c = __cosf(q);
    V3 fl{frec[0], frec[1], frec[2]};
    V3 fa{frec[3], frec[4], frec[5]};
    V3 tl = fl + cl;
    V3 ta = fa + ca;
    float tau;
    if (AX == 0) tau = ta.z;
    else if (AX == 1) tau = ta.y;
    else tau = -ta.y;

    V3 R0, R1, R2;
    make_R<AX>(C, s, c, R0, R1, R2);
    V3 p{C[9], C[10], C[11]};
    V3 nl = tl.x * R0 + tl.y * R1 + tl.z * R2;   // R @ tl (columns)
    V3 na = ta.x * R0 + ta.y * R1 + ta.z * R2 + cross(p, nl);
    cl = nl;
    ca = na;
    return tau;
}

// ---------- main kernel ----------
// No allocator-forcing attributes: rounds 2/5/7 showed any occupancy cap on
// this kernel triggers catastrophic scratch spill. Pressure is reduced
// structurally: fl/fa parked in LDS across a __syncthreads() fence.
__global__ __launch_bounds__(BLK) void rnea_main(
    const float* __restrict__ q_g, const float* __restrict__ qd_g,
    const float* __restrict__ qdd_g, const float* __restrict__ cst,
    float* __restrict__ out, int nbatch) {
    __shared__ float sC[CST_TOT];
    __shared__ float sF[BLK * FREC];   // per-thread fl/fa records, 44 KB
    const int t = threadIdx.x;
    const int row = blockIdx.x * BLK + t;

    if (t < CST_TOT) sC[t] = cst[t];
    __syncthreads();

    const bool ok = row < nbatch;
    const size_t go = (size_t)row * NDOF;
    float q[NDOF], qd[NDOF];
    V3 vl{0.f, 0.f, 0.f}, va{0.f, 0.f, 0.f}, al{0.f, 0.f, 9.81f}, aa{0.f, 0.f, 0.f};
    float* frec = sF + t * FREC;

    if (ok) {
        // direct per-thread loads: 7 contiguous floats per array, one clause each
#pragma unroll
        for (int d = 0; d < NDOF; d++) q[d] = q_g[go + d];
#pragma unroll
        for (int d = 0; d < NDOF; d++) qd[d] = qd_g[go + d];
        float qdd[NDOF];
#pragma unroll
        for (int d = 0; d < NDOF; d++) qdd[d] = qdd_g[go + d];

        // axis sequence: z, y, z, -y, z, y, z
        fwd_step<0>(sC + 0 * CST_STRIDE, frec + 0 * 6, q[0], qd[0], qdd[0], vl, va, al, aa);
        fwd_step<1>(sC + 1 * CST_STRIDE, frec + 1 * 6, q[1], qd[1], qdd[1], vl, va, al, aa);
        fwd_step<0>(sC + 2 * CST_STRIDE, frec + 2 * 6, q[2], qd[2], qdd[2], vl, va, al, aa);
        fwd_step<2>(sC + 3 * CST_STRIDE, frec + 3 * 6, q[3], qd[3], qdd[3], vl, va, al, aa);
        fwd_step<0>(sC + 4 * CST_STRIDE, frec + 4 * 6, q[4], qd[4], qdd[4], vl, va, al, aa);
        fwd_step<1>(sC + 5 * CST_STRIDE, frec + 5 * 6, q[5], qd[5], qdd[5], vl, va, al, aa);
        fwd_step<0>(sC + 6 * CST_STRIDE, frec + 6 * 6, q[6], qd[6], qdd[6], vl, va, al, aa);
    }

    // LDS fence: blocks store->load forwarding / promotion of sF (the whole
    // point — ends fl/fa register live ranges at the fwd stores).
    __syncthreads();

    if (ok) {
        V3 cl{0.f, 0.f, 0.f}, ca{0.f, 0.f, 0.f};
        float tau[NDOF];
        tau[6] = bwd_step<0>(sC + 6 * CST_STRIDE, frec + 6 * 6, q[6], cl, ca);
        tau[5] = bwd_step<1>(sC + 5 * CST_STRIDE, frec + 5 * 6, q[5], cl, ca);
        tau[4] = bwd_step<0>(sC + 4 * CST_STRIDE, frec + 4 * 6, q[4], cl, ca);
        tau[3] = bwd_step<2>(sC + 3 * CST_STRIDE, frec + 3 * 6, q[3], cl, ca);
        tau[2] = bwd_step<0>(sC + 2 * CST_STRIDE, frec + 2 * 6, q[2], cl, ca);
        tau[1] = bwd_step<1>(sC + 1 * CST_STRIDE, frec + 1 * 6, q[1], cl, ca);
        tau[0] = bwd_step<0>(sC + 0 * CST_STRIDE, frec + 0 * 6, q[0], cl, ca);

#pragma unroll
        for (int d = 0; d < NDOF; d++)
            out[go + d] = tau[d] + sC[d * CST_STRIDE + 22] * qd[d];
    }
}

extern "C" void kernel_launch(void* const* d_in, const int* in_sizes, int n_in,
                              void* d_out, int out_size, void* d_ws, size_t ws_size,
                              hipStream_t stream) {
    const float* q = (const float*)d_in[0];
    const float* qd = (const float*)d_in[1];
    const float* qdd = (const float*)d_in[2];
    const float* rot_fix = (const float*)d_in[3];
    const float* trans_fix = (const float*)d_in[4];
    // d_in[5] = joint_axes: compile-time constant in the reference (z,y,z,-y,z,y,z)
    const float* mass = (const float*)d_in[6];
    const float* com = (const float*)d_in[7];
    const float* inertia = (const float*)d_in[8];
    const float* damping = (const float*)d_in[9];
    float* out = (float*)d_out;
    float* cst = (float*)d_ws;  // 7*24*4 = 672 B

    const int n_elem = in_sizes[0];  // B * 7
    const int B = n_elem / NDOF;
    const int grid = (B + BLK - 1) / BLK;

    rnea_prep<<<1, 64, 0, stream>>>(rot_fix, trans_fix, mass, com, inertia, damping, cst);
    rnea_main<<<grid, BLK, 0, stream>>>(q, qd, qdd, cst, out, B);
}